// Round 11
// baseline (207.523 us; speedup 1.0000x reference)
//
#include <hip/hip_runtime.h>

#define N_NODES 20000
#define N_EDGES 320000
#define IN_F    168
#define HID     256
#define K1P     192   // GEMM-1 K (IN_F zero-padded to multiple of 64)
#define XS      192   // xb row stride in shorts (384B, 128B-aligned)
#define NF4     42    // IN_F / 4
#define X4      48    // K1P / 4 (short4 per padded row)
#define CAP     96    // fixed bucket capacity (max degree; P(deg>=96) ~ e^-80)
#define E2      (N_EDGES / 2)
#define ASTR1   200   // fused1 LDS A row stride (shorts): 400B (16B-mult)
#define ASTR2   264   // fused2 LDS A row stride (shorts): 528B (16B-mult)

typedef __attribute__((ext_vector_type(8))) short bf16x8;
typedef __attribute__((ext_vector_type(4))) float f32x4;
typedef __attribute__((ext_vector_type(2))) float f32x2;

__device__ __forceinline__ short f2bf(float f) {
    union { float f; unsigned u; } v; v.f = f;
    unsigned r = v.u + 0x7FFFu + ((v.u >> 16) & 1u);
    return (short)(r >> 16);
}
__device__ __forceinline__ f32x2 bfp(unsigned u) {
    f32x2 r;
    r.x = __uint_as_float(u << 16);
    r.y = __uint_as_float(u & 0xFFFF0000u);
    return r;
}

// ---------------- fused prep: x->bf16 (192-padded), W->bf16, edge deg/count ----
__global__ void prep_all(const float* __restrict__ x, short* __restrict__ xb,
                         const float* __restrict__ W1, const float* __restrict__ W2,
                         short* __restrict__ w1b, short* __restrict__ w2b,
                         const int* __restrict__ ei, const float* __restrict__ ew,
                         float* __restrict__ deg, int* __restrict__ counts) {
    const int xTot  = N_NODES * X4;   // 960000
    const int w1Tot = 256 * X4;       // 12288
    const int w2Tot = 256 * 64;       // 16384
    int i = blockIdx.x * 256 + threadIdx.x;
    if (i < xTot) {
        int n  = i / X4;
        int k4 = i - n * X4;
        short4 o;
        if (k4 < NF4) {
            float4 v = *(const float4*)(x + (size_t)n * IN_F + k4 * 4);
            o = make_short4(f2bf(v.x), f2bf(v.y), f2bf(v.z), f2bf(v.w));
        } else {
            o = make_short4(0, 0, 0, 0);
        }
        *(short4*)(xb + (size_t)n * XS + k4 * 4) = o;
        return;
    }
    i -= xTot;
    if (i < w1Tot) {
        int r  = i / X4;
        int k4 = i - r * X4;
        short4 o;
        if (k4 < NF4) {
            float4 v = *(const float4*)(W1 + (size_t)r * IN_F + k4 * 4);
            o = make_short4(f2bf(v.x), f2bf(v.y), f2bf(v.z), f2bf(v.w));
        } else {
            o = make_short4(0, 0, 0, 0);
        }
        *(short4*)(w1b + (size_t)r * K1P + k4 * 4) = o;
        return;
    }
    i -= w1Tot;
    if (i < w2Tot) {
        int r  = i >> 6;
        int c4 = i & 63;
        float4 v = *(const float4*)(W2 + (size_t)r * HID + c4 * 4);
        *(short4*)(w2b + (size_t)r * HID + c4 * 4) =
            make_short4(f2bf(v.x), f2bf(v.y), f2bf(v.z), f2bf(v.w));
        return;
    }
    i -= w2Tot;
    if (i < N_EDGES) {
        int d = ei[N_EDGES + i];
        atomicAdd(&deg[d], ew[i]);
        atomicAdd(&counts[d], 1);
    }
}

// ---------------- scatter into fixed-stride buckets (no scan needed) ----------
// packed edge record: .x = src node, .y = norm as float bits.
// bucket n occupies er[n*CAP .. n*CAP+CAP); slots [count, pad8(count)) zeroed
// by tail threads (no-op records: src=0, w=0.0).
__global__ void scatter_edges(const int* __restrict__ ei, const float* __restrict__ ew,
                              const float* __restrict__ deg,
                              const int* __restrict__ counts,
                              int* __restrict__ cursor, int2* __restrict__ er) {
    int t = blockIdx.x * 256 + threadIdx.x;
    if (t < E2) {
        int2   s2 = *(const int2*)(ei + 2 * t);
        int2   d2 = *(const int2*)(ei + N_EDGES + 2 * t);
        float2 w2 = *(const float2*)(ew + 2 * t);
        float nm0 = rsqrtf(deg[s2.x] + 1.0f) * w2.x * rsqrtf(deg[d2.x] + 1.0f);
        int c0 = atomicAdd(&cursor[d2.x], 1);
        if (c0 < CAP) er[d2.x * CAP + c0] = make_int2(s2.x, __float_as_int(nm0));
        float nm1 = rsqrtf(deg[s2.y] + 1.0f) * w2.y * rsqrtf(deg[d2.y] + 1.0f);
        int c1 = atomicAdd(&cursor[d2.y], 1);
        if (c1 < CAP) er[d2.y * CAP + c1] = make_int2(s2.y, __float_as_int(nm1));
        return;
    }
    int n = t - E2;
    if (n < N_NODES) {
        int base = n * CAP;
        int p   = base + counts[n];
        int end = base + ((counts[n] + 7) & ~7);
        for (; p < end; ++p) er[p] = make_int2(0, 0);
    }
}

// ---------------- fused layer 1: agg(xb)->LDS(16 rows); GEMM 16x256 -> h1 bf16 -
// 1250 blocks x 16 rows (M = 1250*16 exactly). Phase A: wave w aggregates nodes
// w*4..w*4+3 (identical loop to the proven split agg_x) into LDS rows. Phase B:
// wave w computes C[16 x 64] for cols [64w,64w+64): A-frags from LDS, W-frags
// directly from L2-hot w1b (98KB), bias+ReLU epilogue.
__global__ __launch_bounds__(256) void fused1(
    const short* __restrict__ xb, const float* __restrict__ deg,
    const int* __restrict__ counts, const int2* __restrict__ er,
    const short* __restrict__ w1b, const float* __restrict__ b1,
    short* __restrict__ h1h)
{
    __shared__ short sA[16 * ASTR1];
    const int tid  = threadIdx.x;
    const int wave = tid >> 6;
    const int lane = tid & 63;

    // ---- phase A: aggregate 4 nodes per wave into sA ----
    {
        bool act = lane < NF4;
        int lo4 = act ? lane * 4 : 0;
        for (int i = 0; i < 4; ++i) {
            int r = wave * 4 + i;
            int n = blockIdx.x * 16 + r;
            float di = rsqrtf(deg[n] + 1.0f);
            float sw = di * di;
            uint2 sv = *(const uint2*)(xb + (size_t)n * XS + lo4);
            f32x2 a01 = bfp(sv.x) * sw;
            f32x2 a23 = bfp(sv.y) * sw;
            int p0 = n * CAP;
            int p1 = p0 + ((counts[n] + 7) & ~7);
            for (int p = p0; p < p1; p += 8) {
                const int4* e4 = (const int4*)(er + p);
                int4 eA = e4[0], eB = e4[1], eC = e4[2], eD = e4[3];
                uint2 r0 = *(const uint2*)(xb + (size_t)eA.x * XS + lo4);
                uint2 r1 = *(const uint2*)(xb + (size_t)eA.z * XS + lo4);
                uint2 r2 = *(const uint2*)(xb + (size_t)eB.x * XS + lo4);
                uint2 r3 = *(const uint2*)(xb + (size_t)eB.z * XS + lo4);
                uint2 r4 = *(const uint2*)(xb + (size_t)eC.x * XS + lo4);
                uint2 r5 = *(const uint2*)(xb + (size_t)eC.z * XS + lo4);
                uint2 r6 = *(const uint2*)(xb + (size_t)eD.x * XS + lo4);
                uint2 r7 = *(const uint2*)(xb + (size_t)eD.z * XS + lo4);
                float w0 = __int_as_float(eA.y), w1 = __int_as_float(eA.w);
                float w2 = __int_as_float(eB.y), w3 = __int_as_float(eB.w);
                float w4 = __int_as_float(eC.y), w5 = __int_as_float(eC.w);
                float w6 = __int_as_float(eD.y), w7 = __int_as_float(eD.w);
                a01 += bfp(r0.x) * w0; a23 += bfp(r0.y) * w0;
                a01 += bfp(r1.x) * w1; a23 += bfp(r1.y) * w1;
                a01 += bfp(r2.x) * w2; a23 += bfp(r2.y) * w2;
                a01 += bfp(r3.x) * w3; a23 += bfp(r3.y) * w3;
                a01 += bfp(r4.x) * w4; a23 += bfp(r4.y) * w4;
                a01 += bfp(r5.x) * w5; a23 += bfp(r5.y) * w5;
                a01 += bfp(r6.x) * w6; a23 += bfp(r6.y) * w6;
                a01 += bfp(r7.x) * w7; a23 += bfp(r7.y) * w7;
            }
            if (act) {
                *(short4*)&sA[r * ASTR1 + lane * 4] =
                    make_short4(f2bf(a01.x), f2bf(a01.y), f2bf(a23.x), f2bf(a23.y));
            } else if (lane < 48) {
                *(short4*)&sA[r * ASTR1 + lane * 4] = make_short4(0, 0, 0, 0);
            }
        }
    }
    __syncthreads();

    // ---- phase B: GEMM 16x64 per wave, K=192 (6 ksteps) ----
    const int l16  = lane & 15;
    const int quad = lane >> 4;
    const int wc   = wave * 64;
    f32x4 acc0 = {0,0,0,0}, acc1 = {0,0,0,0}, acc2 = {0,0,0,0}, acc3 = {0,0,0,0};
    const short* wp0 = w1b + (size_t)(wc + l16) * K1P + quad * 8;
    for (int ks = 0; ks < 6; ++ks) {
        int ko = ks * 32;
        bf16x8 af  = *(const bf16x8*)&sA[l16 * ASTR1 + ko + quad * 8];
        bf16x8 wf0 = *(const bf16x8*)(wp0 + ko);
        bf16x8 wf1 = *(const bf16x8*)(wp0 + 16 * K1P + ko);
        bf16x8 wf2 = *(const bf16x8*)(wp0 + 32 * K1P + ko);
        bf16x8 wf3 = *(const bf16x8*)(wp0 + 48 * K1P + ko);
        acc0 = __builtin_amdgcn_mfma_f32_16x16x32_bf16(af, wf0, acc0, 0, 0, 0);
        acc1 = __builtin_amdgcn_mfma_f32_16x16x32_bf16(af, wf1, acc1, 0, 0, 0);
        acc2 = __builtin_amdgcn_mfma_f32_16x16x32_bf16(af, wf2, acc2, 0, 0, 0);
        acc3 = __builtin_amdgcn_mfma_f32_16x16x32_bf16(af, wf3, acc3, 0, 0, 0);
    }
    const int row0 = blockIdx.x * 16 + quad * 4;
    const float bb0 = b1[wc + l16];
    const float bb1 = b1[wc + 16 + l16];
    const float bb2 = b1[wc + 32 + l16];
    const float bb3 = b1[wc + 48 + l16];
    #pragma unroll
    for (int r = 0; r < 4; ++r) {
        size_t rb = (size_t)(row0 + r) * HID + wc + l16;
        float v0 = acc0[r] + bb0; v0 = v0 > 0.f ? v0 : 0.f;
        float v1 = acc1[r] + bb1; v1 = v1 > 0.f ? v1 : 0.f;
        float v2 = acc2[r] + bb2; v2 = v2 > 0.f ? v2 : 0.f;
        float v3 = acc3[r] + bb3; v3 = v3 > 0.f ? v3 : 0.f;
        h1h[rb]      = f2bf(v0);
        h1h[rb + 16] = f2bf(v1);
        h1h[rb + 32] = f2bf(v2);
        h1h[rb + 48] = f2bf(v3);
    }
}

// ---------------- fused layer 2: agg(h1h)->LDS(16 rows); GEMM 16x256 -> out f32
__global__ __launch_bounds__(256) void fused2(
    const short* __restrict__ h1h, const float* __restrict__ deg,
    const int* __restrict__ counts, const int2* __restrict__ er,
    const short* __restrict__ w2b, const float* __restrict__ b2,
    float* __restrict__ out)
{
    __shared__ short sA[16 * ASTR2];
    const int tid  = threadIdx.x;
    const int wave = tid >> 6;
    const int lane = tid & 63;

    // ---- phase A: aggregate 4 nodes per wave into sA (K=256) ----
    {
        int lo4 = lane * 4;
        for (int i = 0; i < 4; ++i) {
            int r = wave * 4 + i;
            int n = blockIdx.x * 16 + r;
            float di = rsqrtf(deg[n] + 1.0f);
            float sw = di * di;
            uint2 sv = *(const uint2*)(h1h + (size_t)n * HID + lo4);
            f32x2 a01 = bfp(sv.x) * sw;
            f32x2 a23 = bfp(sv.y) * sw;
            int p0 = n * CAP;
            int p1 = p0 + ((counts[n] + 7) & ~7);
            for (int p = p0; p < p1; p += 8) {
                const int4* e4 = (const int4*)(er + p);
                int4 eA = e4[0], eB = e4[1], eC = e4[2], eD = e4[3];
                uint2 r0 = *(const uint2*)(h1h + (size_t)eA.x * HID + lo4);
                uint2 r1 = *(const uint2*)(h1h + (size_t)eA.z * HID + lo4);
                uint2 r2 = *(const uint2*)(h1h + (size_t)eB.x * HID + lo4);
                uint2 r3 = *(const uint2*)(h1h + (size_t)eB.z * HID + lo4);
                uint2 r4 = *(const uint2*)(h1h + (size_t)eC.x * HID + lo4);
                uint2 r5 = *(const uint2*)(h1h + (size_t)eC.z * HID + lo4);
                uint2 r6 = *(const uint2*)(h1h + (size_t)eD.x * HID + lo4);
                uint2 r7 = *(const uint2*)(h1h + (size_t)eD.z * HID + lo4);
                float w0 = __int_as_float(eA.y), w1 = __int_as_float(eA.w);
                float w2 = __int_as_float(eB.y), w3 = __int_as_float(eB.w);
                float w4 = __int_as_float(eC.y), w5 = __int_as_float(eC.w);
                float w6 = __int_as_float(eD.y), w7 = __int_as_float(eD.w);
                a01 += bfp(r0.x) * w0; a23 += bfp(r0.y) * w0;
                a01 += bfp(r1.x) * w1; a23 += bfp(r1.y) * w1;
                a01 += bfp(r2.x) * w2; a23 += bfp(r2.y) * w2;
                a01 += bfp(r3.x) * w3; a23 += bfp(r3.y) * w3;
                a01 += bfp(r4.x) * w4; a23 += bfp(r4.y) * w4;
                a01 += bfp(r5.x) * w5; a23 += bfp(r5.y) * w5;
                a01 += bfp(r6.x) * w6; a23 += bfp(r6.y) * w6;
                a01 += bfp(r7.x) * w7; a23 += bfp(r7.y) * w7;
            }
            *(short4*)&sA[r * ASTR2 + lo4] =
                make_short4(f2bf(a01.x), f2bf(a01.y), f2bf(a23.x), f2bf(a23.y));
        }
    }
    __syncthreads();

    // ---- phase B: GEMM 16x64 per wave, K=256 (8 ksteps) ----
    const int l16 = lane & 15;
    const int q   = lane >> 4;
    const int wc  = wave * 64;
    f32x4 acc0 = {0,0,0,0}, acc1 = {0,0,0,0}, acc2 = {0,0,0,0}, acc3 = {0,0,0,0};
    const short* wp0 = w2b + (size_t)(wc + l16) * HID + q * 8;
    for (int ks = 0; ks < 8; ++ks) {
        int ko = ks * 32;
        bf16x8 af  = *(const bf16x8*)&sA[l16 * ASTR2 + ko + q * 8];
        bf16x8 wf0 = *(const bf16x8*)(wp0 + ko);
        bf16x8 wf1 = *(const bf16x8*)(wp0 + 16 * HID + ko);
        bf16x8 wf2 = *(const bf16x8*)(wp0 + 32 * HID + ko);
        bf16x8 wf3 = *(const bf16x8*)(wp0 + 48 * HID + ko);
        acc0 = __builtin_amdgcn_mfma_f32_16x16x32_bf16(af, wf0, acc0, 0, 0, 0);
        acc1 = __builtin_amdgcn_mfma_f32_16x16x32_bf16(af, wf1, acc1, 0, 0, 0);
        acc2 = __builtin_amdgcn_mfma_f32_16x16x32_bf16(af, wf2, acc2, 0, 0, 0);
        acc3 = __builtin_amdgcn_mfma_f32_16x16x32_bf16(af, wf3, acc3, 0, 0, 0);
    }
    const int row0 = blockIdx.x * 16 + q * 4;
    const float bb0 = b2[wc + l16];
    const float bb1 = b2[wc + 16 + l16];
    const float bb2 = b2[wc + 32 + l16];
    const float bb3 = b2[wc + 48 + l16];
    #pragma unroll
    for (int r = 0; r < 4; ++r) {
        size_t rb = (size_t)(row0 + r) * HID + wc + l16;
        float v0 = acc0[r] + bb0; v0 = v0 > 0.f ? v0 : 0.f;
        float v1 = acc1[r] + bb1; v1 = v1 > 0.f ? v1 : 0.f;
        float v2 = acc2[r] + bb2; v2 = v2 > 0.f ? v2 : 0.f;
        float v3 = acc3[r] + bb3; v3 = v3 > 0.f ? v3 : 0.f;
        out[rb]      = v0;
        out[rb + 16] = v1;
        out[rb + 32] = v2;
        out[rb + 48] = v3;
    }
}

// ---------------- launch ----------------

extern "C" void kernel_launch(void* const* d_in, const int* in_sizes, int n_in,
                              void* d_out, int out_size, void* d_ws, size_t ws_size,
                              hipStream_t stream) {
    const float* x  = (const float*)d_in[0];
    const int*   ei = (const int*)d_in[1];
    const float* ew = (const float*)d_in[2];
    const float* W1 = (const float*)d_in[3];
    const float* b1 = (const float*)d_in[4];
    const float* W2 = (const float*)d_in[5];
    const float* b2 = (const float*)d_in[6];
    float* out = (float*)d_out;

    char* ws = (char*)d_ws;
    float* deg      = (float*)(ws);                 // 20000 f32 (raw degree sums)
    int*   counts   = (int*)(ws + 80000);           // 20000 i32
    int*   cursor   = (int*)(ws + 160000);          // 20000 i32
    int2*  er       = (int2*)(ws + 240000);         // 20000*96 int2 -> 15,600,000
    short* h1h      = (short*)(ws + 15600000);      // 20000x256 bf16 -> 25,840,000
    short* w1b      = (short*)(ws + 25840000);      // 256x192 -> 25,938,304
    short* w2b      = (short*)(ws + 25938304);      // 256x256 -> 26,069,376
    short* xb       = (short*)(ws + 26069376);      // 20000x192 bf16 -> 33,749,376

    hipMemsetAsync(d_ws, 0, 240000, stream);        // deg + counts + cursor

    const int prep_tot = N_NODES * X4 + 256 * X4 + 256 * 64 + N_EDGES; // 1308672
    prep_all<<<(prep_tot + 255) / 256, 256, 0, stream>>>(
        x, xb, W1, W2, w1b, w2b, ei, ew, deg, counts);
    const int sc_blocks = (E2 + N_NODES + 255) / 256;  // 704
    scatter_edges<<<sc_blocks, 256, 0, stream>>>(ei, ew, deg, counts, cursor, er);

    const int ftiles = N_NODES / 16;                 // 1250 (exact)
    fused1<<<ftiles, 256, 0, stream>>>(xb, deg, counts, er, w1b, b1, h1h);
    fused2<<<ftiles, 256, 0, stream>>>(h1h, deg, counts, er, w2b, b2, out);
}

// Round 13
// 197.690 us; speedup vs baseline: 1.0497x; 1.0497x over previous
//
#include <hip/hip_runtime.h>

#define N_NODES 20000
#define N_EDGES 320000
#define IN_F    168
#define HID     256
#define K1P     192   // GEMM-1 K (IN_F zero-padded to multiple of 64)
#define XS      192   // xb row stride in shorts (384B, 128B-aligned)
#define NF4     42    // IN_F / 4
#define X4      48    // K1P / 4 (short4 per padded row)
#define CAP     96    // fixed bucket capacity (max degree; P(deg>=96) ~ e^-80)
#define E2      (N_EDGES / 2)

typedef __attribute__((ext_vector_type(8))) short bf16x8;
typedef __attribute__((ext_vector_type(4))) float f32x4;
typedef __attribute__((ext_vector_type(2))) float f32x2;
typedef __attribute__((ext_vector_type(4))) int   i32x4;   // NT-loadable int4

__device__ __forceinline__ short f2bf(float f) {
    union { float f; unsigned u; } v; v.f = f;
    unsigned r = v.u + 0x7FFFu + ((v.u >> 16) & 1u);
    return (short)(r >> 16);
}
__device__ __forceinline__ f32x2 bfp(unsigned u) {
    f32x2 r;
    r.x = __uint_as_float(u << 16);
    r.y = __uint_as_float(u & 0xFFFF0000u);
    return r;
}

// ---------------- fused prep: x->bf16 (192-padded), W->bf16, edge deg/count ----
__global__ void prep_all(const float* __restrict__ x, short* __restrict__ xb,
                         const float* __restrict__ W1, const float* __restrict__ W2,
                         short* __restrict__ w1b, short* __restrict__ w2b,
                         const int* __restrict__ ei, const float* __restrict__ ew,
                         float* __restrict__ deg, int* __restrict__ counts) {
    const int xTot  = N_NODES * X4;   // 960000
    const int w1Tot = 256 * X4;       // 12288
    const int w2Tot = 256 * 64;       // 16384
    int i = blockIdx.x * 256 + threadIdx.x;
    if (i < xTot) {
        int n  = i / X4;
        int k4 = i - n * X4;
        short4 o;
        if (k4 < NF4) {
            float4 v = *(const float4*)(x + (size_t)n * IN_F + k4 * 4);
            o = make_short4(f2bf(v.x), f2bf(v.y), f2bf(v.z), f2bf(v.w));
        } else {
            o = make_short4(0, 0, 0, 0);
        }
        *(short4*)(xb + (size_t)n * XS + k4 * 4) = o;
        return;
    }
    i -= xTot;
    if (i < w1Tot) {
        int r  = i / X4;
        int k4 = i - r * X4;
        short4 o;
        if (k4 < NF4) {
            float4 v = *(const float4*)(W1 + (size_t)r * IN_F + k4 * 4);
            o = make_short4(f2bf(v.x), f2bf(v.y), f2bf(v.z), f2bf(v.w));
        } else {
            o = make_short4(0, 0, 0, 0);
        }
        *(short4*)(w1b + (size_t)r * K1P + k4 * 4) = o;
        return;
    }
    i -= w1Tot;
    if (i < w2Tot) {
        int r  = i >> 6;
        int c4 = i & 63;
        float4 v = *(const float4*)(W2 + (size_t)r * HID + c4 * 4);
        *(short4*)(w2b + (size_t)r * HID + c4 * 4) =
            make_short4(f2bf(v.x), f2bf(v.y), f2bf(v.z), f2bf(v.w));
        return;
    }
    i -= w2Tot;
    if (i < N_EDGES) {
        int d = ei[N_EDGES + i];
        atomicAdd(&deg[d], ew[i]);
        atomicAdd(&counts[d], 1);
    }
}

// ---------------- scatter into fixed-stride buckets (no scan needed) ----------
// packed edge record: .x = src node, .y = norm as float bits.
// bucket n occupies er[n*CAP .. n*CAP+CAP); slots [count, pad8(count)) zeroed
// by tail threads (no-op records: src=0, w=0.0).
__global__ void scatter_edges(const int* __restrict__ ei, const float* __restrict__ ew,
                              const float* __restrict__ deg,
                              const int* __restrict__ counts,
                              int* __restrict__ cursor, int2* __restrict__ er) {
    int t = blockIdx.x * 256 + threadIdx.x;
    if (t < E2) {
        int2   s2 = *(const int2*)(ei + 2 * t);
        int2   d2 = *(const int2*)(ei + N_EDGES + 2 * t);
        float2 w2 = *(const float2*)(ew + 2 * t);
        float nm0 = rsqrtf(deg[s2.x] + 1.0f) * w2.x * rsqrtf(deg[d2.x] + 1.0f);
        int c0 = atomicAdd(&cursor[d2.x], 1);
        if (c0 < CAP) er[d2.x * CAP + c0] = make_int2(s2.x, __float_as_int(nm0));
        float nm1 = rsqrtf(deg[s2.y] + 1.0f) * w2.y * rsqrtf(deg[d2.y] + 1.0f);
        int c1 = atomicAdd(&cursor[d2.y], 1);
        if (c1 < CAP) er[d2.y * CAP + c1] = make_int2(s2.y, __float_as_int(nm1));
        return;
    }
    int n = t - E2;
    if (n < N_NODES) {
        int base = n * CAP;
        int p   = base + counts[n];
        int end = base + ((counts[n] + 7) & ~7);
        for (; p < end; ++p) er[p] = make_int2(0, 0);
    }
}

// ---------------- gathers (Agg BEFORE GEMM; emit bf16 A operand) ----------------
// buckets 8-padded at fixed stride CAP: single full-batch loop, NT i32x4 er loads
// (er is streamed once -> keep it out of L2 so the feature table stays resident),
// packed f32x2 FMA.

// layer 1: agg from bf16 xb rows (384B stride); lanes 0..41 own short4.
__global__ __launch_bounds__(256) void agg_x(const short* __restrict__ xb,
                                             const float* __restrict__ deg,
                                             const int* __restrict__ counts,
                                             const int2* __restrict__ er,
                                             short* __restrict__ ax) {
    int wave = threadIdx.x >> 6;
    int lane = threadIdx.x & 63;
    int n = blockIdx.x * 4 + wave;
    bool act = lane < NF4;
    int lo4 = act ? lane * 4 : 0;                  // inactive lanes read row start (safe)
    float di = rsqrtf(deg[n] + 1.0f);
    float sw = di * di;
    uint2 sv = *(const uint2*)(xb + (size_t)n * XS + lo4);
    f32x2 a01 = bfp(sv.x) * sw;
    f32x2 a23 = bfp(sv.y) * sw;

    int p0 = n * CAP;
    int p1 = p0 + ((counts[n] + 7) & ~7);          // padded bucket length
    for (int p = p0; p < p1; p += 8) {
        const i32x4* e4 = (const i32x4*)(er + p);  // 16B-aligned
        i32x4 eA = __builtin_nontemporal_load(e4);
        i32x4 eB = __builtin_nontemporal_load(e4 + 1);
        i32x4 eC = __builtin_nontemporal_load(e4 + 2);
        i32x4 eD = __builtin_nontemporal_load(e4 + 3);
        uint2 r0 = *(const uint2*)(xb + (size_t)eA.x * XS + lo4);
        uint2 r1 = *(const uint2*)(xb + (size_t)eA.z * XS + lo4);
        uint2 r2 = *(const uint2*)(xb + (size_t)eB.x * XS + lo4);
        uint2 r3 = *(const uint2*)(xb + (size_t)eB.z * XS + lo4);
        uint2 r4 = *(const uint2*)(xb + (size_t)eC.x * XS + lo4);
        uint2 r5 = *(const uint2*)(xb + (size_t)eC.z * XS + lo4);
        uint2 r6 = *(const uint2*)(xb + (size_t)eD.x * XS + lo4);
        uint2 r7 = *(const uint2*)(xb + (size_t)eD.z * XS + lo4);
        float w0 = __int_as_float(eA.y), w1 = __int_as_float(eA.w);
        float w2 = __int_as_float(eB.y), w3 = __int_as_float(eB.w);
        float w4 = __int_as_float(eC.y), w5 = __int_as_float(eC.w);
        float w6 = __int_as_float(eD.y), w7 = __int_as_float(eD.w);
        a01 += bfp(r0.x) * w0; a23 += bfp(r0.y) * w0;
        a01 += bfp(r1.x) * w1; a23 += bfp(r1.y) * w1;
        a01 += bfp(r2.x) * w2; a23 += bfp(r2.y) * w2;
        a01 += bfp(r3.x) * w3; a23 += bfp(r3.y) * w3;
        a01 += bfp(r4.x) * w4; a23 += bfp(r4.y) * w4;
        a01 += bfp(r5.x) * w5; a23 += bfp(r5.y) * w5;
        a01 += bfp(r6.x) * w6; a23 += bfp(r6.y) * w6;
        a01 += bfp(r7.x) * w7; a23 += bfp(r7.y) * w7;
    }

    size_t base = (size_t)n * K1P + lane * 4;
    if (act) {
        *(short4*)&ax[base] = make_short4(f2bf(a01.x), f2bf(a01.y),
                                          f2bf(a23.x), f2bf(a23.y));
    } else if (lane < 48) {                        // zero pad cols 168..191
        *(short4*)&ax[base] = make_short4(0, 0, 0, 0);
    }
}

// layer 2: agg from bf16 h1 rows (512B); one short4 per lane.
__global__ __launch_bounds__(256) void agg_h(const short* __restrict__ h1h,
                                             const float* __restrict__ deg,
                                             const int* __restrict__ counts,
                                             const int2* __restrict__ er,
                                             short* __restrict__ ah) {
    int wave = threadIdx.x >> 6;
    int lane = threadIdx.x & 63;
    int n = blockIdx.x * 4 + wave;
    int lo4 = lane * 4;
    float di = rsqrtf(deg[n] + 1.0f);
    float sw = di * di;
    uint2 sv = *(const uint2*)(h1h + (size_t)n * HID + lo4);
    f32x2 a01 = bfp(sv.x) * sw;
    f32x2 a23 = bfp(sv.y) * sw;

    int p0 = n * CAP;
    int p1 = p0 + ((counts[n] + 7) & ~7);
    for (int p = p0; p < p1; p += 8) {
        const i32x4* e4 = (const i32x4*)(er + p);
        i32x4 eA = __builtin_nontemporal_load(e4);
        i32x4 eB = __builtin_nontemporal_load(e4 + 1);
        i32x4 eC = __builtin_nontemporal_load(e4 + 2);
        i32x4 eD = __builtin_nontemporal_load(e4 + 3);
        uint2 r0 = *(const uint2*)(h1h + (size_t)eA.x * HID + lo4);
        uint2 r1 = *(const uint2*)(h1h + (size_t)eA.z * HID + lo4);
        uint2 r2 = *(const uint2*)(h1h + (size_t)eB.x * HID + lo4);
        uint2 r3 = *(const uint2*)(h1h + (size_t)eB.z * HID + lo4);
        uint2 r4 = *(const uint2*)(h1h + (size_t)eC.x * HID + lo4);
        uint2 r5 = *(const uint2*)(h1h + (size_t)eC.z * HID + lo4);
        uint2 r6 = *(const uint2*)(h1h + (size_t)eD.x * HID + lo4);
        uint2 r7 = *(const uint2*)(h1h + (size_t)eD.z * HID + lo4);
        float w0 = __int_as_float(eA.y), w1 = __int_as_float(eA.w);
        float w2 = __int_as_float(eB.y), w3 = __int_as_float(eB.w);
        float w4 = __int_as_float(eC.y), w5 = __int_as_float(eC.w);
        float w6 = __int_as_float(eD.y), w7 = __int_as_float(eD.w);
        a01 += bfp(r0.x) * w0; a23 += bfp(r0.y) * w0;
        a01 += bfp(r1.x) * w1; a23 += bfp(r1.y) * w1;
        a01 += bfp(r2.x) * w2; a23 += bfp(r2.y) * w2;
        a01 += bfp(r3.x) * w3; a23 += bfp(r3.y) * w3;
        a01 += bfp(r4.x) * w4; a23 += bfp(r4.y) * w4;
        a01 += bfp(r5.x) * w5; a23 += bfp(r5.y) * w5;
        a01 += bfp(r6.x) * w6; a23 += bfp(r6.y) * w6;
        a01 += bfp(r7.x) * w7; a23 += bfp(r7.y) * w7;
    }

    *(short4*)&ah[(size_t)n * HID + lo4] = make_short4(f2bf(a01.x), f2bf(a01.y),
                                                       f2bf(a23.x), f2bf(a23.y));
}

// ---------------- MFMA GEMM (pure bf16) with fused bias+ReLU epilogue ----------
#define LDS_STRIDE 72

__global__ __launch_bounds__(256) void gemm_bf(const short* __restrict__ Ah,
                                               const short* __restrict__ Wh,
                                               const float* __restrict__ bias,
                                               float* __restrict__ Cf,
                                               short* __restrict__ Cbf,
                                               int M, int Ks, int nsteps, int mode) {
    __shared__ short sAh[64 * LDS_STRIDE];
    __shared__ short sWh[64 * LDS_STRIDE];

    const int idx   = blockIdx.x;
    const int group = idx >> 5;
    const int xcd   = idx & 7;
    const int slot  = (idx >> 3) & 3;
    const int mt    = group * 8 + xcd;
    const int mtiles = (M + 63) >> 6;
    if (mt >= mtiles) return;
    const int bm = mt * 64;
    const int bn = slot * 64;

    const int tid  = threadIdx.x;
    const int lane = tid & 63;
    const int wv   = tid >> 6;
    const int l16  = lane & 15;
    const int quad = lane >> 4;
    const int wm   = (wv & 1) * 32;
    const int wn   = (wv >> 1) * 32;

    const int srow = tid >> 2;
    const int sseg = (tid & 3) * 16;
    int arow = bm + srow; if (arow >= M) arow = M - 1;
    const short* gAh = Ah + (size_t)arow * Ks;
    const short* gWh = Wh + (size_t)(bn + srow) * Ks;
    const int lds_off = srow * LDS_STRIDE + sseg;

    f32x4 acc00 = {0,0,0,0}, acc01 = {0,0,0,0}, acc10 = {0,0,0,0}, acc11 = {0,0,0,0};

    int4 pah0 = *(const int4*)(gAh + sseg), pah1 = *(const int4*)(gAh + sseg + 8);
    int4 pwh0 = *(const int4*)(gWh + sseg), pwh1 = *(const int4*)(gWh + sseg + 8);

    for (int ks = 0; ks < nsteps; ++ks) {
        *(int4*)&sAh[lds_off] = pah0; *(int4*)&sAh[lds_off + 8] = pah1;
        *(int4*)&sWh[lds_off] = pwh0; *(int4*)&sWh[lds_off + 8] = pwh1;
        __syncthreads();
        if (ks + 1 < nsteps) {
            int o = (ks + 1) * 64 + sseg;
            pah0 = *(const int4*)(gAh + o); pah1 = *(const int4*)(gAh + o + 8);
            pwh0 = *(const int4*)(gWh + o); pwh1 = *(const int4*)(gWh + o + 8);
        }
        #pragma unroll
        for (int o = 0; o < 2; ++o) {
            const int a0 = (wm + l16) * LDS_STRIDE + o * 32 + quad * 8;
            const int a1 = a0 + 16 * LDS_STRIDE;
            const int w0 = (wn + l16) * LDS_STRIDE + o * 32 + quad * 8;
            const int w1 = w0 + 16 * LDS_STRIDE;
            bf16x8 ah0 = *(const bf16x8*)&sAh[a0];
            bf16x8 ah1 = *(const bf16x8*)&sAh[a1];
            bf16x8 wh0 = *(const bf16x8*)&sWh[w0];
            bf16x8 wh1 = *(const bf16x8*)&sWh[w1];
            acc00 = __builtin_amdgcn_mfma_f32_16x16x32_bf16(ah0, wh0, acc00, 0, 0, 0);
            acc01 = __builtin_amdgcn_mfma_f32_16x16x32_bf16(ah0, wh1, acc01, 0, 0, 0);
            acc10 = __builtin_amdgcn_mfma_f32_16x16x32_bf16(ah1, wh0, acc10, 0, 0, 0);
            acc11 = __builtin_amdgcn_mfma_f32_16x16x32_bf16(ah1, wh1, acc11, 0, 0, 0);
        }
        __syncthreads();
    }

    const int colb = bn + wn + l16;
    const int rowb = bm + wm + quad * 4;
    const float b0 = bias[colb];
    const float b1 = bias[colb + 16];
    #pragma unroll
    for (int r = 0; r < 4; ++r) {
        int row = rowb + r;
        if (row < M) {
            float v0 = acc00[r] + b0; v0 = v0 > 0.f ? v0 : 0.f;
            float v1 = acc01[r] + b1; v1 = v1 > 0.f ? v1 : 0.f;
            if (mode == 0) {
                Cbf[(size_t)row * HID + colb]      = f2bf(v0);
                Cbf[(size_t)row * HID + colb + 16] = f2bf(v1);
            } else {
                Cf[(size_t)row * HID + colb]      = v0;
                Cf[(size_t)row * HID + colb + 16] = v1;
            }
        }
        int row2 = row + 16;
        if (row2 < M) {
            float v0 = acc10[r] + b0; v0 = v0 > 0.f ? v0 : 0.f;
            float v1 = acc11[r] + b1; v1 = v1 > 0.f ? v1 : 0.f;
            if (mode == 0) {
                Cbf[(size_t)row2 * HID + colb]      = f2bf(v0);
                Cbf[(size_t)row2 * HID + colb + 16] = f2bf(v1);
            } else {
                Cf[(size_t)row2 * HID + colb]      = v0;
                Cf[(size_t)row2 * HID + colb + 16] = v1;
            }
        }
    }
}

// ---------------- launch ----------------

extern "C" void kernel_launch(void* const* d_in, const int* in_sizes, int n_in,
                              void* d_out, int out_size, void* d_ws, size_t ws_size,
                              hipStream_t stream) {
    const float* x  = (const float*)d_in[0];
    const int*   ei = (const int*)d_in[1];
    const float* ew = (const float*)d_in[2];
    const float* W1 = (const float*)d_in[3];
    const float* b1 = (const float*)d_in[4];
    const float* W2 = (const float*)d_in[5];
    const float* b2 = (const float*)d_in[6];
    float* out = (float*)d_out;

    char* ws = (char*)d_ws;
    float* deg      = (float*)(ws);                 // 20000 f32 (raw degree sums)
    int*   counts   = (int*)(ws + 80000);           // 20000 i32
    int*   cursor   = (int*)(ws + 160000);          // 20000 i32
    int2*  er       = (int2*)(ws + 240000);         // 20000*96 int2 -> 15,600,000
    short* ax       = (short*)(ws + 15600000);      // 20000x192 bf16 (7.68MB)
    short* ah       = (short*)(ws + 15600000);      // 20000x256 bf16 (reuses ax region)
    short* h1h      = (short*)(ws + 25840000);      // 20000x256 bf16 -> 36,080,000
    short* w1b      = (short*)(ws + 36080000);      // 256x192 -> 36,178,304
    short* w2b      = (short*)(ws + 36178304);      // 256x256 -> 36,309,376
    short* xb       = (short*)(ws + 36309376);      // 20000x192 bf16 -> 43,989,376

    hipMemsetAsync(d_ws, 0, 240000, stream);        // deg + counts + cursor

    const int prep_tot = N_NODES * X4 + 256 * X4 + 256 * 64 + N_EDGES; // 1308672
    prep_all<<<(prep_tot + 255) / 256, 256, 0, stream>>>(
        x, xb, W1, W2, w1b, w2b, ei, ew, deg, counts);
    const int sc_blocks = (E2 + N_NODES + 255) / 256;  // 704
    scatter_edges<<<sc_blocks, 256, 0, stream>>>(ei, ew, deg, counts, cursor, er);

    const int mtiles = (N_NODES + 63) / 64;          // 313
    const int gemm_grid = ((mtiles + 7) / 8) * 32;   // 1280

    // layer 1: Agg(bf16 xb) -> ax bf16; GEMM(+b1, ReLU) -> h1 bf16
    agg_x<<<N_NODES / 4, 256, 0, stream>>>(xb, deg, counts, er, ax);
    gemm_bf<<<gemm_grid, 256, 0, stream>>>(ax, w1b, b1, nullptr, h1h,
                                           N_NODES, K1P, 3, 0);
    // layer 2: Agg(bf16 h1) -> ah bf16; GEMM(+b2, ReLU) -> out fp32
    agg_h<<<N_NODES / 4, 256, 0, stream>>>(h1h, deg, counts, er, ah);
    gemm_bf<<<gemm_grid, 256, 0, stream>>>(ah, w2b, b2, out, nullptr,
                                           N_NODES, HID, 4, 1);
}

// Round 14
// 191.287 us; speedup vs baseline: 1.0849x; 1.0335x over previous
//
#include <hip/hip_runtime.h>

#define N_NODES 20000
#define N_EDGES 320000
#define IN_F    168
#define HID     256
#define K1P     192   // GEMM-1 K (IN_F zero-padded to multiple of 64)
#define XS      192   // xb row stride in shorts (384B, 128B-aligned)
#define NF4     42    // IN_F / 4
#define X4      48    // K1P / 4 (short4 per padded row)
#define CAP     96    // fixed bucket capacity (max degree; P(deg>=96) ~ e^-80)
#define E2      (N_EDGES / 2)

typedef __attribute__((ext_vector_type(8))) short bf16x8;
typedef __attribute__((ext_vector_type(4))) float f32x4;
typedef __attribute__((ext_vector_type(2))) float f32x2;

__device__ __forceinline__ short f2bf(float f) {
    union { float f; unsigned u; } v; v.f = f;
    unsigned r = v.u + 0x7FFFu + ((v.u >> 16) & 1u);
    return (short)(r >> 16);
}
__device__ __forceinline__ f32x2 bfp(unsigned u) {
    f32x2 r;
    r.x = __uint_as_float(u << 16);
    r.y = __uint_as_float(u & 0xFFFF0000u);
    return r;
}

// ---------------- fused prep: x->bf16 (192-padded), W->bf16, edge deg/count ----
__global__ void prep_all(const float* __restrict__ x, short* __restrict__ xb,
                         const float* __restrict__ W1, const float* __restrict__ W2,
                         short* __restrict__ w1b, short* __restrict__ w2b,
                         const int* __restrict__ ei, const float* __restrict__ ew,
                         float* __restrict__ deg, int* __restrict__ counts) {
    const int xTot  = N_NODES * X4;   // 960000
    const int w1Tot = 256 * X4;       // 12288
    const int w2Tot = 256 * 64;       // 16384
    int i = blockIdx.x * 256 + threadIdx.x;
    if (i < xTot) {
        int n  = i / X4;
        int k4 = i - n * X4;
        short4 o;
        if (k4 < NF4) {
            float4 v = *(const float4*)(x + (size_t)n * IN_F + k4 * 4);
            o = make_short4(f2bf(v.x), f2bf(v.y), f2bf(v.z), f2bf(v.w));
        } else {
            o = make_short4(0, 0, 0, 0);
        }
        *(short4*)(xb + (size_t)n * XS + k4 * 4) = o;
        return;
    }
    i -= xTot;
    if (i < w1Tot) {
        int r  = i / X4;
        int k4 = i - r * X4;
        short4 o;
        if (k4 < NF4) {
            float4 v = *(const float4*)(W1 + (size_t)r * IN_F + k4 * 4);
            o = make_short4(f2bf(v.x), f2bf(v.y), f2bf(v.z), f2bf(v.w));
        } else {
            o = make_short4(0, 0, 0, 0);
        }
        *(short4*)(w1b + (size_t)r * K1P + k4 * 4) = o;
        return;
    }
    i -= w1Tot;
    if (i < w2Tot) {
        int r  = i >> 6;
        int c4 = i & 63;
        float4 v = *(const float4*)(W2 + (size_t)r * HID + c4 * 4);
        *(short4*)(w2b + (size_t)r * HID + c4 * 4) =
            make_short4(f2bf(v.x), f2bf(v.y), f2bf(v.z), f2bf(v.w));
        return;
    }
    i -= w2Tot;
    if (i < N_EDGES) {
        int d = ei[N_EDGES + i];
        atomicAdd(&deg[d], ew[i]);
        atomicAdd(&counts[d], 1);
    }
}

// ---------------- scatter into fixed-stride buckets (no scan needed) ----------
// packed edge record: .x = src node, .y = norm as float bits.
// bucket n occupies er[n*CAP .. n*CAP+CAP); slots [count, pad8(count)) zeroed
// by tail threads (no-op records: src=0, w=0.0).
__global__ void scatter_edges(const int* __restrict__ ei, const float* __restrict__ ew,
                              const float* __restrict__ deg,
                              const int* __restrict__ counts,
                              int* __restrict__ cursor, int2* __restrict__ er) {
    int t = blockIdx.x * 256 + threadIdx.x;
    if (t < E2) {
        int2   s2 = *(const int2*)(ei + 2 * t);
        int2   d2 = *(const int2*)(ei + N_EDGES + 2 * t);
        float2 w2 = *(const float2*)(ew + 2 * t);
        float nm0 = rsqrtf(deg[s2.x] + 1.0f) * w2.x * rsqrtf(deg[d2.x] + 1.0f);
        int c0 = atomicAdd(&cursor[d2.x], 1);
        if (c0 < CAP) er[d2.x * CAP + c0] = make_int2(s2.x, __float_as_int(nm0));
        float nm1 = rsqrtf(deg[s2.y] + 1.0f) * w2.y * rsqrtf(deg[d2.y] + 1.0f);
        int c1 = atomicAdd(&cursor[d2.y], 1);
        if (c1 < CAP) er[d2.y * CAP + c1] = make_int2(s2.y, __float_as_int(nm1));
        return;
    }
    int n = t - E2;
    if (n < N_NODES) {
        int base = n * CAP;
        int p   = base + counts[n];
        int end = base + ((counts[n] + 7) & ~7);
        for (; p < end; ++p) er[p] = make_int2(0, 0);
    }
}

// ---------------- gathers (Agg BEFORE GEMM; emit bf16 A operand) ----------------
// buckets 8-padded at fixed stride CAP: single full-batch loop, int4 er loads,
// packed f32x2 FMA. Loop bound from counts (padded to 8).

// layer 1: agg from bf16 xb rows (384B stride); lanes 0..41 own short4.
__global__ __launch_bounds__(256) void agg_x(const short* __restrict__ xb,
                                             const float* __restrict__ deg,
                                             const int* __restrict__ counts,
                                             const int2* __restrict__ er,
                                             short* __restrict__ ax) {
    int wave = threadIdx.x >> 6;
    int lane = threadIdx.x & 63;
    int n = blockIdx.x * 4 + wave;
    bool act = lane < NF4;
    int lo4 = act ? lane * 4 : 0;                  // inactive lanes read row start (safe)
    float di = rsqrtf(deg[n] + 1.0f);
    float sw = di * di;
    uint2 sv = *(const uint2*)(xb + (size_t)n * XS + lo4);
    f32x2 a01 = bfp(sv.x) * sw;
    f32x2 a23 = bfp(sv.y) * sw;

    int p0 = n * CAP;
    int p1 = p0 + ((counts[n] + 7) & ~7);          // padded bucket length
    for (int p = p0; p < p1; p += 8) {
        const int4* e4 = (const int4*)(er + p);    // 16B-aligned
        int4 eA = e4[0], eB = e4[1], eC = e4[2], eD = e4[3];
        uint2 r0 = *(const uint2*)(xb + (size_t)eA.x * XS + lo4);
        uint2 r1 = *(const uint2*)(xb + (size_t)eA.z * XS + lo4);
        uint2 r2 = *(const uint2*)(xb + (size_t)eB.x * XS + lo4);
        uint2 r3 = *(const uint2*)(xb + (size_t)eB.z * XS + lo4);
        uint2 r4 = *(const uint2*)(xb + (size_t)eC.x * XS + lo4);
        uint2 r5 = *(const uint2*)(xb + (size_t)eC.z * XS + lo4);
        uint2 r6 = *(const uint2*)(xb + (size_t)eD.x * XS + lo4);
        uint2 r7 = *(const uint2*)(xb + (size_t)eD.z * XS + lo4);
        float w0 = __int_as_float(eA.y), w1 = __int_as_float(eA.w);
        float w2 = __int_as_float(eB.y), w3 = __int_as_float(eB.w);
        float w4 = __int_as_float(eC.y), w5 = __int_as_float(eC.w);
        float w6 = __int_as_float(eD.y), w7 = __int_as_float(eD.w);
        a01 += bfp(r0.x) * w0; a23 += bfp(r0.y) * w0;
        a01 += bfp(r1.x) * w1; a23 += bfp(r1.y) * w1;
        a01 += bfp(r2.x) * w2; a23 += bfp(r2.y) * w2;
        a01 += bfp(r3.x) * w3; a23 += bfp(r3.y) * w3;
        a01 += bfp(r4.x) * w4; a23 += bfp(r4.y) * w4;
        a01 += bfp(r5.x) * w5; a23 += bfp(r5.y) * w5;
        a01 += bfp(r6.x) * w6; a23 += bfp(r6.y) * w6;
        a01 += bfp(r7.x) * w7; a23 += bfp(r7.y) * w7;
    }

    size_t base = (size_t)n * K1P + lane * 4;
    if (act) {
        *(short4*)&ax[base] = make_short4(f2bf(a01.x), f2bf(a01.y),
                                          f2bf(a23.x), f2bf(a23.y));
    } else if (lane < 48) {                        // zero pad cols 168..191
        *(short4*)&ax[base] = make_short4(0, 0, 0, 0);
    }
}

// layer 2: agg from bf16 h1 rows (512B); one short4 per lane.
__global__ __launch_bounds__(256) void agg_h(const short* __restrict__ h1h,
                                             const float* __restrict__ deg,
                                             const int* __restrict__ counts,
                                             const int2* __restrict__ er,
                                             short* __restrict__ ah) {
    int wave = threadIdx.x >> 6;
    int lane = threadIdx.x & 63;
    int n = blockIdx.x * 4 + wave;
    int lo4 = lane * 4;
    float di = rsqrtf(deg[n] + 1.0f);
    float sw = di * di;
    uint2 sv = *(const uint2*)(h1h + (size_t)n * HID + lo4);
    f32x2 a01 = bfp(sv.x) * sw;
    f32x2 a23 = bfp(sv.y) * sw;

    int p0 = n * CAP;
    int p1 = p0 + ((counts[n] + 7) & ~7);
    for (int p = p0; p < p1; p += 8) {
        const int4* e4 = (const int4*)(er + p);
        int4 eA = e4[0], eB = e4[1], eC = e4[2], eD = e4[3];
        uint2 r0 = *(const uint2*)(h1h + (size_t)eA.x * HID + lo4);
        uint2 r1 = *(const uint2*)(h1h + (size_t)eA.z * HID + lo4);
        uint2 r2 = *(const uint2*)(h1h + (size_t)eB.x * HID + lo4);
        uint2 r3 = *(const uint2*)(h1h + (size_t)eB.z * HID + lo4);
        uint2 r4 = *(const uint2*)(h1h + (size_t)eC.x * HID + lo4);
        uint2 r5 = *(const uint2*)(h1h + (size_t)eC.z * HID + lo4);
        uint2 r6 = *(const uint2*)(h1h + (size_t)eD.x * HID + lo4);
        uint2 r7 = *(const uint2*)(h1h + (size_t)eD.z * HID + lo4);
        float w0 = __int_as_float(eA.y), w1 = __int_as_float(eA.w);
        float w2 = __int_as_float(eB.y), w3 = __int_as_float(eB.w);
        float w4 = __int_as_float(eC.y), w5 = __int_as_float(eC.w);
        float w6 = __int_as_float(eD.y), w7 = __int_as_float(eD.w);
        a01 += bfp(r0.x) * w0; a23 += bfp(r0.y) * w0;
        a01 += bfp(r1.x) * w1; a23 += bfp(r1.y) * w1;
        a01 += bfp(r2.x) * w2; a23 += bfp(r2.y) * w2;
        a01 += bfp(r3.x) * w3; a23 += bfp(r3.y) * w3;
        a01 += bfp(r4.x) * w4; a23 += bfp(r4.y) * w4;
        a01 += bfp(r5.x) * w5; a23 += bfp(r5.y) * w5;
        a01 += bfp(r6.x) * w6; a23 += bfp(r6.y) * w6;
        a01 += bfp(r7.x) * w7; a23 += bfp(r7.y) * w7;
    }

    *(short4*)&ah[(size_t)n * HID + lo4] = make_short4(f2bf(a01.x), f2bf(a01.y),
                                                       f2bf(a23.x), f2bf(a23.y));
}

// ---------------- MFMA GEMM (pure bf16) with fused bias+ReLU epilogue ----------
#define LDS_STRIDE 72

__global__ __launch_bounds__(256) void gemm_bf(const short* __restrict__ Ah,
                                               const short* __restrict__ Wh,
                                               const float* __restrict__ bias,
                                               float* __restrict__ Cf,
                                               short* __restrict__ Cbf,
                                               int M, int Ks, int nsteps, int mode) {
    __shared__ short sAh[64 * LDS_STRIDE];
    __shared__ short sWh[64 * LDS_STRIDE];

    const int idx   = blockIdx.x;
    const int group = idx >> 5;
    const int xcd   = idx & 7;
    const int slot  = (idx >> 3) & 3;
    const int mt    = group * 8 + xcd;
    const int mtiles = (M + 63) >> 6;
    if (mt >= mtiles) return;
    const int bm = mt * 64;
    const int bn = slot * 64;

    const int tid  = threadIdx.x;
    const int lane = tid & 63;
    const int wv   = tid >> 6;
    const int l16  = lane & 15;
    const int quad = lane >> 4;
    const int wm   = (wv & 1) * 32;
    const int wn   = (wv >> 1) * 32;

    const int srow = tid >> 2;
    const int sseg = (tid & 3) * 16;
    int arow = bm + srow; if (arow >= M) arow = M - 1;
    const short* gAh = Ah + (size_t)arow * Ks;
    const short* gWh = Wh + (size_t)(bn + srow) * Ks;
    const int lds_off = srow * LDS_STRIDE + sseg;

    f32x4 acc00 = {0,0,0,0}, acc01 = {0,0,0,0}, acc10 = {0,0,0,0}, acc11 = {0,0,0,0};

    int4 pah0 = *(const int4*)(gAh + sseg), pah1 = *(const int4*)(gAh + sseg + 8);
    int4 pwh0 = *(const int4*)(gWh + sseg), pwh1 = *(const int4*)(gWh + sseg + 8);

    for (int ks = 0; ks < nsteps; ++ks) {
        *(int4*)&sAh[lds_off] = pah0; *(int4*)&sAh[lds_off + 8] = pah1;
        *(int4*)&sWh[lds_off] = pwh0; *(int4*)&sWh[lds_off + 8] = pwh1;
        __syncthreads();
        if (ks + 1 < nsteps) {
            int o = (ks + 1) * 64 + sseg;
            pah0 = *(const int4*)(gAh + o); pah1 = *(const int4*)(gAh + o + 8);
            pwh0 = *(const int4*)(gWh + o); pwh1 = *(const int4*)(gWh + o + 8);
        }
        #pragma unroll
        for (int o = 0; o < 2; ++o) {
            const int a0 = (wm + l16) * LDS_STRIDE + o * 32 + quad * 8;
            const int a1 = a0 + 16 * LDS_STRIDE;
            const int w0 = (wn + l16) * LDS_STRIDE + o * 32 + quad * 8;
            const int w1 = w0 + 16 * LDS_STRIDE;
            bf16x8 ah0 = *(const bf16x8*)&sAh[a0];
            bf16x8 ah1 = *(const bf16x8*)&sAh[a1];
            bf16x8 wh0 = *(const bf16x8*)&sWh[w0];
            bf16x8 wh1 = *(const bf16x8*)&sWh[w1];
            acc00 = __builtin_amdgcn_mfma_f32_16x16x32_bf16(ah0, wh0, acc00, 0, 0, 0);
            acc01 = __builtin_amdgcn_mfma_f32_16x16x32_bf16(ah0, wh1, acc01, 0, 0, 0);
            acc10 = __builtin_amdgcn_mfma_f32_16x16x32_bf16(ah1, wh0, acc10, 0, 0, 0);
            acc11 = __builtin_amdgcn_mfma_f32_16x16x32_bf16(ah1, wh1, acc11, 0, 0, 0);
        }
        __syncthreads();
    }

    const int colb = bn + wn + l16;
    const int rowb = bm + wm + quad * 4;
    const float b0 = bias[colb];
    const float b1 = bias[colb + 16];
    #pragma unroll
    for (int r = 0; r < 4; ++r) {
        int row = rowb + r;
        if (row < M) {
            float v0 = acc00[r] + b0; v0 = v0 > 0.f ? v0 : 0.f;
            float v1 = acc01[r] + b1; v1 = v1 > 0.f ? v1 : 0.f;
            if (mode == 0) {
                Cbf[(size_t)row * HID + colb]      = f2bf(v0);
                Cbf[(size_t)row * HID + colb + 16] = f2bf(v1);
            } else {
                Cf[(size_t)row * HID + colb]      = v0;
                Cf[(size_t)row * HID + colb + 16] = v1;
            }
        }
        int row2 = row + 16;
        if (row2 < M) {
            float v0 = acc10[r] + b0; v0 = v0 > 0.f ? v0 : 0.f;
            float v1 = acc11[r] + b1; v1 = v1 > 0.f ? v1 : 0.f;
            if (mode == 0) {
                Cbf[(size_t)row2 * HID + colb]      = f2bf(v0);
                Cbf[(size_t)row2 * HID + colb + 16] = f2bf(v1);
            } else {
                Cf[(size_t)row2 * HID + colb]      = v0;
                Cf[(size_t)row2 * HID + colb + 16] = v1;
            }
        }
    }
}

// ---------------- launch ----------------

extern "C" void kernel_launch(void* const* d_in, const int* in_sizes, int n_in,
                              void* d_out, int out_size, void* d_ws, size_t ws_size,
                              hipStream_t stream) {
    const float* x  = (const float*)d_in[0];
    const int*   ei = (const int*)d_in[1];
    const float* ew = (const float*)d_in[2];
    const float* W1 = (const float*)d_in[3];
    const float* b1 = (const float*)d_in[4];
    const float* W2 = (const float*)d_in[5];
    const float* b2 = (const float*)d_in[6];
    float* out = (float*)d_out;

    char* ws = (char*)d_ws;
    float* deg      = (float*)(ws);                 // 20000 f32 (raw degree sums)
    int*   counts   = (int*)(ws + 80000);           // 20000 i32
    int*   cursor   = (int*)(ws + 160000);          // 20000 i32
    int2*  er       = (int2*)(ws + 240000);         // 20000*96 int2 -> 15,600,000
    short* ax       = (short*)(ws + 15600000);      // 20000x192 bf16 (7.68MB)
    short* ah       = (short*)(ws + 15600000);      // 20000x256 bf16 (reuses ax region)
    short* h1h      = (short*)(ws + 25840000);      // 20000x256 bf16 -> 36,080,000
    short* w1b      = (short*)(ws + 36080000);      // 256x192 -> 36,178,304
    short* w2b      = (short*)(ws + 36178304);      // 256x256 -> 36,309,376
    short* xb       = (short*)(ws + 36309376);      // 20000x192 bf16 -> 43,989,376

    hipMemsetAsync(d_ws, 0, 240000, stream);        // deg + counts + cursor

    const int prep_tot = N_NODES * X4 + 256 * X4 + 256 * 64 + N_EDGES; // 1308672
    prep_all<<<(prep_tot + 255) / 256, 256, 0, stream>>>(
        x, xb, W1, W2, w1b, w2b, ei, ew, deg, counts);
    const int sc_blocks = (E2 + N_NODES + 255) / 256;  // 704
    scatter_edges<<<sc_blocks, 256, 0, stream>>>(ei, ew, deg, counts, cursor, er);

    const int mtiles = (N_NODES + 63) / 64;          // 313
    const int gemm_grid = ((mtiles + 7) / 8) * 32;   // 1280

    // layer 1: Agg(bf16 xb) -> ax bf16; GEMM(+b1, ReLU) -> h1 bf16
    agg_x<<<N_NODES / 4, 256, 0, stream>>>(xb, deg, counts, er, ax);
    gemm_bf<<<gemm_grid, 256, 0, stream>>>(ax, w1b, b1, nullptr, h1h,
                                           N_NODES, K1P, 3, 0);
    // layer 2: Agg(bf16 h1) -> ah bf16; GEMM(+b2, ReLU) -> out fp32
    agg_h<<<N_NODES / 4, 256, 0, stream>>>(h1h, deg, counts, er, ah);
    gemm_bf<<<gemm_grid, 256, 0, stream>>>(ah, w2b, b2, out, nullptr,
                                           N_NODES, HID, 4, 1);
}